// Round 11
// baseline (3702.917 us; speedup 1.0000x reference)
//
#include <hip/hip_runtime.h>
#include <hip/hip_bf16.h>
#include <cstdint>
#include <cstddef>

// Problem constants
#define BB 32
#define TT 256
#define HID 512

typedef __attribute__((ext_vector_type(8))) short short8v;   // 8 bf16
typedef __attribute__((ext_vector_type(4))) float float4v;
typedef __attribute__((ext_vector_type(4))) unsigned int uint4v;
typedef __attribute__((ext_vector_type(2))) unsigned int uint2v;

__device__ __forceinline__ float bf2f(unsigned short u) {
  return __uint_as_float(((unsigned int)u) << 16);
}
__device__ __forceinline__ unsigned short f2bf(float f) {
  unsigned int x = __float_as_uint(f);
  x += 0x7fffu + ((x >> 16) & 1u);    // RNE
  return (unsigned short)(x >> 16);
}
// fast NaN-safe gates
__device__ __forceinline__ float fsig(float x) {
  return 1.f / (1.f + __expf(-x));
}
__device__ __forceinline__ float ftanh(float x) {
  return 1.f - 2.f / (__expf(2.f * x) + 1.f);
}

// coherent (agent-scope, cache-bypass) ops for cross-WG state.
__device__ __forceinline__ void stg4u_cohere(unsigned short* p, uint4v v) {
  asm volatile("global_store_dwordx4 %0, %1, off sc0 sc1"
               :: "v"(p), "v"(v) : "memory");
}
__device__ __forceinline__ void ldg4u_cohere_issue(uint4v& d, const unsigned short* p) {
  asm volatile("global_load_dwordx4 %0, %1, off sc0 sc1"
               : "=v"(d) : "v"(p) : "memory");
}
__device__ __forceinline__ void wait_vm0() {
  asm volatile("s_waitcnt vmcnt(0)" ::: "memory");
  __builtin_amdgcn_sched_barrier(0);
}

// =============== fused prep: 8 weight transposes + embed + hbuf zeroing ====
// blocks [0,2432): 64x64 transpose tiles; [2432,3456): embedding;
// [3456,3472): coherent-zero hbufA+hbufB (512KB) — MUST be sc0sc1 stores so
// no dirty L2 lines can later write back over fresh stamps.
__global__ __launch_bounds__(256) void prep_all(
    const float* __restrict__ w_fw0, const float* __restrict__ w_bw0,
    const float* __restrict__ w_fw1, const float* __restrict__ w_bw1,
    unsigned short* __restrict__ wxt0f, unsigned short* __restrict__ wxt0b,
    unsigned short* __restrict__ wxt1f, unsigned short* __restrict__ wxt1b,
    unsigned short* __restrict__ whT0f, unsigned short* __restrict__ whT0b,
    unsigned short* __restrict__ whT1f, unsigned short* __restrict__ whT1b,
    const int* __restrict__ ids, const int* __restrict__ msk,
    const float* __restrict__ emb, const float* __restrict__ memb,
    unsigned short* __restrict__ x0b,
    unsigned short* __restrict__ hzero)
{
  __shared__ float tile[64][65];
  int blk = blockIdx.x;
  int tid = threadIdx.x;
  if (blk < 2432) {
    const float* W; unsigned short* dst; int Kreal, Kpad, base;
    if (blk < 192)       { W = w_fw0; dst = wxt0f; Kreal = 350;  Kpad = 384;  base = 0; }
    else if (blk < 384)  { W = w_bw0; dst = wxt0b; Kreal = 350;  Kpad = 384;  base = 192; }
    else if (blk < 896)  { W = w_fw1; dst = wxt1f; Kreal = 1024; Kpad = 1024; base = 384; }
    else if (blk < 1408) { W = w_bw1; dst = wxt1b; Kreal = 1024; Kpad = 1024; base = 896; }
    else if (blk < 1664) { W = w_fw0 + (size_t)350 * 2048;  dst = whT0f; Kreal = 512; Kpad = 512; base = 1408; }
    else if (blk < 1920) { W = w_bw0 + (size_t)350 * 2048;  dst = whT0b; Kreal = 512; Kpad = 512; base = 1664; }
    else if (blk < 2176) { W = w_fw1 + (size_t)1024 * 2048; dst = whT1f; Kreal = 512; Kpad = 512; base = 1920; }
    else                 { W = w_bw1 + (size_t)1024 * 2048; dst = whT1b; Kreal = 512; Kpad = 512; base = 2176; }
    int rel = blk - base;
    int n0 = (rel & 31) * 64;
    int k0 = (rel >> 5) * 64;
#pragma unroll
    for (int i = 0; i < 4; ++i) {
      int e = tid + 256 * i;
      int r = e >> 4, c4 = (e & 15) * 4;
      float4 v = make_float4(0.f, 0.f, 0.f, 0.f);
      if (k0 + r < Kreal) v = *(const float4*)(W + (size_t)(k0 + r) * 2048 + n0 + c4);
      tile[r][c4 + 0] = v.x; tile[r][c4 + 1] = v.y;
      tile[r][c4 + 2] = v.z; tile[r][c4 + 3] = v.w;
    }
    __syncthreads();
    int nl = tid >> 2;
    int kg = (tid & 3) * 16;
    unsigned int pk[4], pk2[4];
#pragma unroll
    for (int jj = 0; jj < 4; ++jj) {
      unsigned short lo = f2bf(tile[kg + jj * 2 + 0][nl]);
      unsigned short hi = f2bf(tile[kg + jj * 2 + 1][nl]);
      pk[jj] = (unsigned int)lo | ((unsigned int)hi << 16);
    }
#pragma unroll
    for (int jj = 0; jj < 4; ++jj) {
      unsigned short lo = f2bf(tile[kg + 8 + jj * 2 + 0][nl]);
      unsigned short hi = f2bf(tile[kg + 8 + jj * 2 + 1][nl]);
      pk2[jj] = (unsigned int)lo | ((unsigned int)hi << 16);
    }
    size_t off = (size_t)(n0 + nl) * Kpad + k0 + kg;
    *(uint4*)(dst + off) = make_uint4(pk[0], pk[1], pk[2], pk[3]);
    *(uint4*)(dst + off + 8) = make_uint4(pk2[0], pk2[1], pk2[2], pk2[3]);
  } else if (blk < 3456) {
    int r = blk - 2432;
    int bt = r * 8 + (tid >> 5);
    int id = ids[bt];
    int m  = msk[bt];
    const float* er = emb  + (size_t)id * 300;
    const float* mr = memb + (size_t)m * 50;
    for (int d = tid & 31; d < 384; d += 32) {
      float v = (d < 300) ? er[d] : (d < 350 ? mr[d - 300] : 0.f);
      x0b[(size_t)bt * 384 + d] = f2bf(v);
    }
  } else {
    // coherent-zero 512KB of stamp chunks (32768 chunks, 16 blocks)
    int r = blk - 3456;           // 0..15
    unsigned short* p = hzero + ((size_t)r * 2048 + tid) * 8;
    uint4v z = (uint4v)0u;
#pragma unroll
    for (int i = 0; i < 8; ++i)
      stg4u_cohere(p + (size_t)i * 256 * 8, z);
  }
}

// ---- MFMA bf16 GEMM (fw+bw fused via z) -> xq[pos][2048][32] bf16 --------
__global__ __launch_bounds__(256) void gemm_xproj2(
    const unsigned short* __restrict__ A,     // [8192][Kpad] bf16
    const unsigned short* __restrict__ wxtF, const unsigned short* __restrict__ wxtB,
    const float* __restrict__ biasF, const float* __restrict__ biasB,
    unsigned short* __restrict__ xqF, unsigned short* __restrict__ xqB,
    int Kpad, int nkb)
{
  __shared__ unsigned short ws_s[128 * 64];
  __shared__ unsigned short xs_s[32 * 64];
  __shared__ float bias_s[128];
  int z = blockIdx.z;
  const unsigned short* wxt = z ? wxtB : wxtF;
  const float* bias = z ? biasB : biasF;
  unsigned short* xq = z ? xqB : xqF;
  int tid = threadIdx.x;
  int lane = tid & 63;
  int w = tid >> 6;
  int pos = blockIdx.x;
  int n0 = blockIdx.y * 128;
  if (tid < 128) bias_s[tid] = bias[n0 + tid];

  float4v acc[2][2];
#pragma unroll
  for (int i = 0; i < 2; ++i)
#pragma unroll
    for (int j = 0; j < 2; ++j) acc[i][j] = (float4v)0.f;

  int brow = tid >> 3;
  int seg = tid & 7;
  for (int kb = 0; kb < nkb; ++kb) {
    int k0 = kb * 64;
    __syncthreads();
    {
      const unsigned short* src = A + (size_t)(brow * 256 + pos) * Kpad + k0 + seg * 8;
      uint4 v = *(const uint4*)src;
      int o = (brow * 128 + seg * 16) ^ ((brow & 7) << 4);
      *(uint4*)((char*)xs_s + o) = v;
    }
#pragma unroll
    for (int i = 0; i < 4; ++i) {
      int n = i * 32 + brow;
      const unsigned short* src = wxt + (size_t)(n0 + n) * Kpad + k0 + seg * 8;
      uint4 v = *(const uint4*)src;
      int o = (n * 128 + seg * 16) ^ ((n & 7) << 4);
      *(uint4*)((char*)ws_s + o) = v;
    }
    __syncthreads();
#pragma unroll
    for (int kin = 0; kin < 64; kin += 32) {
      int kl = kin + ((lane >> 4) << 3);
      short8v afrag[2], bfrag[2];
#pragma unroll
      for (int nt = 0; nt < 2; ++nt) {
        int nl = w * 32 + nt * 16 + (lane & 15);
        int o = (nl * 128 + kl * 2) ^ ((nl & 7) << 4);
        afrag[nt] = *(const short8v*)((const char*)ws_s + o);
      }
#pragma unroll
      for (int bt = 0; bt < 2; ++bt) {
        int bl = bt * 16 + (lane & 15);
        int o = (bl * 128 + kl * 2) ^ ((bl & 7) << 4);
        bfrag[bt] = *(const short8v*)((const char*)xs_s + o);
      }
#pragma unroll
      for (int nt = 0; nt < 2; ++nt)
#pragma unroll
        for (int bt = 0; bt < 2; ++bt)
          acc[nt][bt] = __builtin_amdgcn_mfma_f32_16x16x32_bf16(
              afrag[nt], bfrag[bt], acc[nt][bt], 0, 0, 0);
    }
  }
  unsigned short* outp = xq + (size_t)pos * 65536;
#pragma unroll
  for (int nt = 0; nt < 2; ++nt) {
#pragma unroll
    for (int bt = 0; bt < 2; ++bt) {
#pragma unroll
      for (int reg = 0; reg < 4; ++reg) {
        int nl = w * 32 + nt * 16 + ((lane >> 4) << 2) + reg;
        int b = bt * 16 + (lane & 15);
        float v = acc[nt][bt][reg] + bias_s[nl];
        outp[(size_t)(n0 + nl) * 32 + b] = f2bf(v);
      }
    }
  }
}

// ========== MFMA bidirectional LSTM recurrence — dataflow-synced ==========
// Grid 128 WGs x 256 thr: wg<64 -> fw, else bw. Each WG owns 8 hidden units.
// NO barrier: h crosses WGs as 16B stamped chunks {stamp, 4 bf16, stamp}
// (sc0sc1 stores / poll-retry sc0sc1 loads). Ping-pong parity is WAR-safe by
// dataflow induction: overwriting parity p at step t+2 requires having
// consumed ALL stamps t+2, which every WG posts only after its step-t read
// of parity p completed.
// hbuf layout: chunk (dir, parity, b, kb) at ((dir*2+parity)*4096+b*128+kb)*16B
//   kb in [0,128): k-values [4kb, 4kb+4).
__global__ __launch_bounds__(256) void lstm_mfma(
    const unsigned short* __restrict__ xq_fw, const unsigned short* __restrict__ xq_bw,
    const unsigned short* __restrict__ whT_fw, const unsigned short* __restrict__ whT_bw,
    const int* __restrict__ length,
    unsigned short* __restrict__ out,   // (B,T,1024) bf16
    unsigned short* __restrict__ hbuf)  // [dir][2][32][128] 16B stamped chunks
{
  extern __shared__ char smem[];
  // Wl: bytes [0, 32768)       [32 rows c=q*8+d][512 k] bf16, swz ^((row&7)<<4)
  // hs: bytes [32768, 65536)   [32 b][512 k] bf16, same swz
  float* zs = (float*)(smem + 65536);                       // [32][32] f32
  unsigned short* hb_st = (unsigned short*)(smem + 69632);  // [32][8]
  unsigned short* ob_st = (unsigned short*)(smem + 70144);  // [32][8]
  int tid = threadIdx.x;
  int wg = blockIdx.x;
  int dir = wg >> 6;
  int widx = wg & 63;
  int u0 = widx << 3;
  const unsigned short* xq = dir ? xq_bw : xq_fw;
  const unsigned short* whT = dir ? whT_bw : whT_fw;

  // ---- stage W_h slice once ----
  {
    int r = tid >> 3;
    int q = r >> 3, d = r & 7;
    const unsigned short* src = whT + (size_t)(q * 512 + u0 + d) * 512 + (tid & 7) * 8;
    int ob = r * 1024 + (tid & 7) * 16;
    int sw = (r & 7) << 4;
#pragma unroll
    for (int i = 0; i < 8; ++i) {
      uint4 v = *(const uint4*)(src + i * 64);
      *(uint4*)(smem + ((ob + i * 128) ^ sw)) = v;
    }
  }

  // wave/frag constants
  int lane = tid & 63;
  int w = tid >> 6;
  int wr = w >> 1, wc = w & 1;
  int arow = wr * 16 + (lane & 15);
  int bcol = wc * 16 + (lane & 15);
  int chunk16 = (lane >> 4) << 4;
  int asw = (arow & 7) << 4;
  int bsw = (bcol & 7) << 4;
  // finalize constants
  int fu = tid >> 5;
  int fb = tid & 31;
  int ug = u0 + fu;
  int L = length[fb];
  float creg = 0.f;
  // consumer constants
  int pb = tid >> 3;     // batch row this thread stages
  int pseg = tid & 7;    // k-64-block

  // xv preload for t=0
  const unsigned short* xbase = xq + (size_t)ug * 32 + fb;
  float xv0, xv1, xv2, xv3;
  {
    int sl0 = dir ? (TT - 1) : 0;
    const unsigned short* xr = xbase + (size_t)sl0 * 65536;
    xv0 = bf2f(xr[0]);
    xv1 = bf2f(xr[16384]);
    xv2 = bf2f(xr[32768]);
    xv3 = bf2f(xr[49152]);
  }

  for (int t = 0; t < TT; ++t) {
    int sl = dir ? (TT - 1 - t) : t;

    // ---- phase 1: stage h(t-1) into LDS ----
    if (t == 0) {
      int ob = 32768 + pb * 1024 + pseg * 16;
      int sw = (pb & 7) << 4;
      uint4v zv = (uint4v)0u;
#pragma unroll
      for (int i = 0; i < 8; ++i)
        *(uint4v*)(smem + ((ob + i * 128) ^ sw)) = zv;
    } else {
      unsigned stamp = (unsigned)t;
      const unsigned short* cb = hbuf +
          ((size_t)((dir << 1) + (t & 1)) * 4096 + (size_t)pb * 128 + pseg * 16) * 8;
      uint4v c[16];
#pragma unroll
      for (int i = 0; i < 16; ++i) ldg4u_cohere_issue(c[i], cb + i * 8);
      wait_vm0();
      unsigned mask = 0xFFFFu;
      while (true) {
#pragma unroll
        for (int i = 0; i < 16; ++i) {
          if ((mask >> i) & 1u) {
            if (c[i].x == stamp && c[i].w == stamp) {
              int kb = pseg * 16 + i;
              int off = (32768 + pb * 1024 + kb * 8) ^ ((pb & 7) << 4);
              uint2v d2;
              d2.x = c[i].y;
              d2.y = c[i].z;
              *(uint2v*)(smem + off) = d2;
              mask &= ~(1u << i);
            }
          }
        }
        if (!mask) break;
        __builtin_amdgcn_s_sleep(1);
#pragma unroll
        for (int i = 0; i < 16; ++i)
          if ((mask >> i) & 1u) ldg4u_cohere_issue(c[i], cb + i * 8);
        wait_vm0();
      }
    }
    __syncthreads();

    // ---- phase 3: MFMA z[32 gate-cols][32 b] = Wl(32x512) @ hs(512x32) ----
    float4v acc = (float4v)0.f;
#pragma unroll
    for (int ks = 0; ks < 16; ++ks) {
      int kb = ks * 64 + chunk16;
      short8v af = *(const short8v*)(smem + (size_t)arow * 1024 + (kb ^ asw));
      short8v bf = *(const short8v*)(smem + 32768 + (size_t)bcol * 1024 + (kb ^ bsw));
      acc = __builtin_amdgcn_mfma_f32_16x16x32_bf16(af, bf, acc, 0, 0, 0);
    }
#pragma unroll
    for (int r = 0; r < 4; ++r) {
      int row = wr * 16 + ((lane >> 4) << 2) + r;
      zs[row * 32 + bcol] = acc[r];
    }
    __syncthreads();

    // ---- phase 5: finalize ----
    {
      bool active = sl < L;
      float z0 = zs[(0 * 8 + fu) * 32 + fb] + xv0;
      float z1 = zs[(1 * 8 + fu) * 32 + fb] + xv1;
      float z2 = zs[(2 * 8 + fu) * 32 + fb] + xv2;
      float z3 = zs[(3 * 8 + fu) * 32 + fb] + xv3;
      int ho = 32768 + fb * 1024 + ((ug * 2) ^ ((fb & 7) << 4));
      float h_old = bf2f(*(const unsigned short*)(smem + ho));
      float si = fsig(z0);
      float sj = ftanh(z1);
      float sf = fsig(z2 + 1.f);
      float so = fsig(z3);
      float cn = sf * creg + si * sj;
      float hn = so * ftanh(cn);
      if (active) creg = cn;
      hb_st[fb * 8 + fu] = f2bf(active ? hn : h_old);
      ob_st[fb * 8 + fu] = f2bf(active ? hn : 0.f);
    }
    __syncthreads();

    // ---- phase 7: publish stamped h chunks; out store; xv prefetch ----
    if (tid < 64) {
      int b = tid >> 1, j = tid & 1;
      uint2v d = *(const uint2v*)(hb_st + b * 8 + j * 4);
      uint4v ch;
      ch.x = (unsigned)(t + 1);
      ch.y = d.x;
      ch.z = d.y;
      ch.w = (unsigned)(t + 1);
      unsigned short* dst = hbuf +
          ((size_t)((dir << 1) + ((t + 1) & 1)) * 4096 + (size_t)b * 128 +
           (2 * widx + j)) * 8;
      stg4u_cohere(dst, ch);
    } else if (tid >= 64 && tid < 96) {
      int b = tid - 64;
      uint4v ov = *(const uint4v*)(ob_st + b * 8);
      *(uint4v*)(out + (size_t)(b * TT + sl) * 1024 + dir * 512 + u0) = ov;
    }

    // prefetch next step's xv (drained by next poll's wait)
    if (t + 1 < TT) {
      int sl2 = dir ? (TT - 2 - t) : (t + 1);
      const unsigned short* xr = xbase + (size_t)sl2 * 65536;
      xv0 = bf2f(xr[0]);
      xv1 = bf2f(xr[16384]);
      xv2 = bf2f(xr[32768]);
      xv3 = bf2f(xr[49152]);
    }
    // no barrier — dataflow (stamps) synchronizes WGs
  }
}

// ---------------- CRF + pooling + final softmax ----------------
__global__ __launch_bounds__(256) void crf_final(
    const unsigned short* __restrict__ out1,   // (B,T,1024) bf16
    const float* __restrict__ crf_w, const float* __restrict__ crf_b,
    const float* __restrict__ trans,
    const int* __restrict__ length,
    const float* __restrict__ lw, const float* __restrict__ lb,
    float* __restrict__ dout)
{
  __shared__ float e[TT][2];
  __shared__ float pw[TT];
  __shared__ float sv[1024];
  __shared__ float red[256];
  int b = blockIdx.x, tid = threadIdx.x;
  int lane = tid & 63, w = tid >> 6;
  const unsigned short* ob = out1 + (size_t)b * TT * 1024;
  for (int t = w; t < TT; t += 4) {
    float a0 = 0.f, a1 = 0.f;
    for (int i = 0; i < 16; ++i) {
      int d = lane + i * 64;
      float v = bf2f(ob[(size_t)t * 1024 + d]);
      a0 += v * crf_w[d * 2];
      a1 += v * crf_w[d * 2 + 1];
    }
    for (int off = 32; off; off >>= 1) {
      a0 += __shfl_down(a0, off);
      a1 += __shfl_down(a1, off);
    }
    if (lane == 0) { e[t][0] = a0 + crf_b[0]; e[t][1] = a1 + crf_b[1]; }
  }
  __syncthreads();
  if (tid == 0) {
    int L = length[b];
    float t00 = trans[0], t01 = trans[1], t10 = trans[2], t11 = trans[3];
    float a0 = e[0][0], a1 = e[0][1];
    {
      float m = fmaxf(a0, a1);
      float e0 = __expf(a0 - m), e1 = __expf(a1 - m);
      pw[0] = (L > 0) ? (e1 / (e0 + e1)) : 0.f;
    }
    for (int t = 1; t < TT; ++t) {
      if (t < L) {
        float x0 = a0 + t00, y0 = a1 + t10;
        float m0 = fmaxf(x0, y0);
        float n0 = m0 + __logf(__expf(x0 - m0) + __expf(y0 - m0)) + e[t][0];
        float x1 = a0 + t01, y1 = a1 + t11;
        float m1 = fmaxf(x1, y1);
        float n1 = m1 + __logf(__expf(x1 - m1) + __expf(y1 - m1)) + e[t][1];
        a0 = n0; a1 = n1;
        float m = fmaxf(a0, a1);
        float e0 = __expf(a0 - m), e1 = __expf(a1 - m);
        pw[t] = e1 / (e0 + e1);
      } else {
        pw[t] = 0.f;
      }
    }
  }
  __syncthreads();
  for (int i = 0; i < 4; ++i) {
    int d = tid + i * 256;
    float s = 0.f;
    for (int t = 0; t < TT; ++t) s += pw[t] * bf2f(ob[(size_t)t * 1024 + d]);
    sv[d] = s;
  }
  __syncthreads();
  float v[3];
  for (int c = 0; c < 3; ++c) {
    float s = 0.f;
    for (int i = 0; i < 4; ++i) {
      int d = tid + i * 256;
      s += sv[d] * lw[d * 3 + c];
    }
    red[tid] = s;
    __syncthreads();
    for (int off = 128; off; off >>= 1) {
      if (tid < off) red[tid] += red[tid + off];
      __syncthreads();
    }
    if (tid == 0) v[c] = red[0] + lb[c];
    __syncthreads();
  }
  if (tid == 0) {
    float m = fmaxf(v[0], fmaxf(v[1], v[2]));
    float e0 = __expf(v[0] - m), e1 = __expf(v[1] - m), e2 = __expf(v[2] - m);
    float s = e0 + e1 + e2;
    dout[b * 3 + 0] = e0 / s;
    dout[b * 3 + 1] = e1 / s;
    dout[b * 3 + 2] = e2 / s;
  }
}

#define LSTM_LDS 70656

static void run_layer(const unsigned short* xq_fw, const unsigned short* xq_bw,
                      const unsigned short* whT_fw, const unsigned short* whT_bw,
                      const int* len, unsigned short* out, unsigned short* hbuf,
                      hipStream_t stream) {
  const unsigned short* a0 = xq_fw; const unsigned short* a1 = xq_bw;
  const unsigned short* a2 = whT_fw; const unsigned short* a3 = whT_bw;
  const int* a4 = len; unsigned short* a5 = out; unsigned short* a6 = hbuf;
  void* args[7] = { &a0, &a1, &a2, &a3, &a4, &a5, &a6 };
  hipError_t err = hipLaunchCooperativeKernel(
      reinterpret_cast<const void*>(lstm_mfma), dim3(128), dim3(256),
      args, LSTM_LDS, stream);
  if (err != hipSuccess) {
    // 128 WGs on 256 CUs co-reside under a plain launch too; dataflow sync
    // has no cooperative-API dependency.
    lstm_mfma<<<128, 256, LSTM_LDS, stream>>>(
        xq_fw, xq_bw, whT_fw, whT_bw, len, out, hbuf);
  }
}

extern "C" void kernel_launch(void* const* d_in, const int* in_sizes, int n_in,
                              void* d_out, int out_size, void* d_ws, size_t ws_size,
                              hipStream_t stream) {
  (void)in_sizes; (void)n_in; (void)out_size; (void)ws_size;
  const int* ids    = (const int*)d_in[0];
  const int* msk    = (const int*)d_in[1];
  const int* len    = (const int*)d_in[2];
  const float* emb  = (const float*)d_in[3];
  const float* memb = (const float*)d_in[4];
  const float* trans= (const float*)d_in[5];
  const float* w_fw0= (const float*)d_in[6];
  const float* b_fw0= (const float*)d_in[7];
  const float* w_bw0= (const float*)d_in[8];
  const float* b_bw0= (const float*)d_in[9];
  const float* w_fw1= (const float*)d_in[10];
  const float* b_fw1= (const float*)d_in[11];
  const float* w_bw1= (const float*)d_in[12];
  const float* b_bw1= (const float*)d_in[13];
  const float* crf_w= (const float*)d_in[14];
  const float* crf_b= (const float*)d_in[15];
  const float* lw   = (const float*)d_in[16];
  const float* lb   = (const float*)d_in[17];
  float* outp = (float*)d_out;

  float* ws = (float*)d_ws;
  unsigned short* x0b   = (unsigned short*)(ws);
  unsigned short* wxt0f = (unsigned short*)(ws + 1572864);
  unsigned short* wxt0b = (unsigned short*)(ws + 1966080);
  unsigned short* wxt1f = (unsigned short*)(ws + 2359296);
  unsigned short* wxt1b = (unsigned short*)(ws + 3407872);
  unsigned short* whT0f = (unsigned short*)(ws + 4456448);
  unsigned short* whT0b = (unsigned short*)(ws + 4980736);
  unsigned short* whT1f = (unsigned short*)(ws + 5505024);
  unsigned short* whT1b = (unsigned short*)(ws + 6029312);
  unsigned short* xqf   = (unsigned short*)(ws + 6553600);
  unsigned short* xqb   = (unsigned short*)(ws + 14942208);
  unsigned short* out0b = (unsigned short*)(ws + 23330816);
  unsigned short* out1b = (unsigned short*)(ws + 27525120);
  unsigned short* hbufA = (unsigned short*)(ws + 31719424);   // 256KB
  unsigned short* hbufB = (unsigned short*)(ws + 31784960);   // 256KB

  (void)hipFuncSetAttribute(reinterpret_cast<const void*>(lstm_mfma),
                            hipFuncAttributeMaxDynamicSharedMemorySize, LSTM_LDS);

  // one launch: 8 weight transposes + embedding + coherent-zero hbufA+hbufB
  prep_all<<<3472, 256, 0, stream>>>(
      w_fw0, w_bw0, w_fw1, w_bw1,
      wxt0f, wxt0b, wxt1f, wxt1b,
      whT0f, whT0b, whT1f, whT1b,
      ids, msk, emb, memb, x0b, hbufA);

  gemm_xproj2<<<dim3(256, 16, 2), 256, 0, stream>>>(
      x0b, wxt0f, wxt0b, b_fw0, b_bw0, xqf, xqb, 384, 6);

  run_layer(xqf, xqb, whT0f, whT0b, len, out0b, hbufA, stream);

  gemm_xproj2<<<dim3(256, 16, 2), 256, 0, stream>>>(
      out0b, wxt1f, wxt1b, b_fw1, b_bw1, xqf, xqb, 1024, 16);

  run_layer(xqf, xqb, whT1f, whT1b, len, out1b, hbufB, stream);

  crf_final<<<32, 256, 0, stream>>>(out1b, crf_w, crf_b, trans, len, lw, lb, outp);
}

// Round 12
// 1901.643 us; speedup vs baseline: 1.9472x; 1.9472x over previous
//
#include <hip/hip_runtime.h>
#include <hip/hip_bf16.h>
#include <cstdint>
#include <cstddef>

// Problem constants
#define BB 32
#define TT 256
#define HID 512

typedef __attribute__((ext_vector_type(8))) short short8v;   // 8 bf16
typedef __attribute__((ext_vector_type(4))) float float4v;
typedef __attribute__((ext_vector_type(4))) unsigned int uint4v;

__device__ __forceinline__ float bf2f(unsigned short u) {
  return __uint_as_float(((unsigned int)u) << 16);
}
__device__ __forceinline__ unsigned short f2bf(float f) {
  unsigned int x = __float_as_uint(f);
  x += 0x7fffu + ((x >> 16) & 1u);    // RNE
  return (unsigned short)(x >> 16);
}
// fast NaN-safe gates
__device__ __forceinline__ float fsig(float x) {
  return 1.f / (1.f + __expf(-x));
}
__device__ __forceinline__ float ftanh(float x) {
  return 1.f - 2.f / (__expf(2.f * x) + 1.f);
}

// coherent (agent-scope, cache-bypass) ops for cross-WG state.
__device__ __forceinline__ void ldg4u_cohere_issue(uint4v& d, const unsigned short* p) {
  asm volatile("global_load_dwordx4 %0, %1, off sc0 sc1"
               : "=v"(d) : "v"(p) : "memory");
}
__device__ __forceinline__ void wait_vm0() {
  asm volatile("s_waitcnt vmcnt(0)" ::: "memory");
  __builtin_amdgcn_sched_barrier(0);
}

// =============== fused prep: 8 weight transposes + embed + zeroing =========
__global__ __launch_bounds__(256) void prep_all(
    const float* __restrict__ w_fw0, const float* __restrict__ w_bw0,
    const float* __restrict__ w_fw1, const float* __restrict__ w_bw1,
    unsigned short* __restrict__ wxt0f, unsigned short* __restrict__ wxt0b,
    unsigned short* __restrict__ wxt1f, unsigned short* __restrict__ wxt1b,
    unsigned short* __restrict__ whT0f, unsigned short* __restrict__ whT0b,
    unsigned short* __restrict__ whT1f, unsigned short* __restrict__ whT1b,
    const int* __restrict__ ids, const int* __restrict__ msk,
    const float* __restrict__ emb, const float* __restrict__ memb,
    unsigned short* __restrict__ x0b,
    float* __restrict__ zero_base)
{
  __shared__ float tile[64][65];
  int blk = blockIdx.x;
  int tid = threadIdx.x;
  if (blk < 2432) {
    const float* W; unsigned short* dst; int Kreal, Kpad, base;
    if (blk < 192)       { W = w_fw0; dst = wxt0f; Kreal = 350;  Kpad = 384;  base = 0; }
    else if (blk < 384)  { W = w_bw0; dst = wxt0b; Kreal = 350;  Kpad = 384;  base = 192; }
    else if (blk < 896)  { W = w_fw1; dst = wxt1f; Kreal = 1024; Kpad = 1024; base = 384; }
    else if (blk < 1408) { W = w_bw1; dst = wxt1b; Kreal = 1024; Kpad = 1024; base = 896; }
    else if (blk < 1664) { W = w_fw0 + (size_t)350 * 2048;  dst = whT0f; Kreal = 512; Kpad = 512; base = 1408; }
    else if (blk < 1920) { W = w_bw0 + (size_t)350 * 2048;  dst = whT0b; Kreal = 512; Kpad = 512; base = 1664; }
    else if (blk < 2176) { W = w_fw1 + (size_t)1024 * 2048; dst = whT1f; Kreal = 512; Kpad = 512; base = 1920; }
    else                 { W = w_bw1 + (size_t)1024 * 2048; dst = whT1b; Kreal = 512; Kpad = 512; base = 2176; }
    int rel = blk - base;
    int n0 = (rel & 31) * 64;
    int k0 = (rel >> 5) * 64;
#pragma unroll
    for (int i = 0; i < 4; ++i) {
      int e = tid + 256 * i;
      int r = e >> 4, c4 = (e & 15) * 4;
      float4 v = make_float4(0.f, 0.f, 0.f, 0.f);
      if (k0 + r < Kreal) v = *(const float4*)(W + (size_t)(k0 + r) * 2048 + n0 + c4);
      tile[r][c4 + 0] = v.x; tile[r][c4 + 1] = v.y;
      tile[r][c4 + 2] = v.z; tile[r][c4 + 3] = v.w;
    }
    __syncthreads();
    int nl = tid >> 2;
    int kg = (tid & 3) * 16;
    unsigned int pk[4], pk2[4];
#pragma unroll
    for (int jj = 0; jj < 4; ++jj) {
      unsigned short lo = f2bf(tile[kg + jj * 2 + 0][nl]);
      unsigned short hi = f2bf(tile[kg + jj * 2 + 1][nl]);
      pk[jj] = (unsigned int)lo | ((unsigned int)hi << 16);
    }
#pragma unroll
    for (int jj = 0; jj < 4; ++jj) {
      unsigned short lo = f2bf(tile[kg + 8 + jj * 2 + 0][nl]);
      unsigned short hi = f2bf(tile[kg + 8 + jj * 2 + 1][nl]);
      pk2[jj] = (unsigned int)lo | ((unsigned int)hi << 16);
    }
    size_t off = (size_t)(n0 + nl) * Kpad + k0 + kg;
    *(uint4*)(dst + off) = make_uint4(pk[0], pk[1], pk[2], pk[3]);
    *(uint4*)(dst + off + 8) = make_uint4(pk2[0], pk2[1], pk2[2], pk2[3]);
  } else if (blk < 3456) {
    int r = blk - 2432;
    int bt = r * 8 + (tid >> 5);
    int id = ids[bt];
    int m  = msk[bt];
    const float* er = emb  + (size_t)id * 300;
    const float* mr = memb + (size_t)m * 50;
    for (int d = tid & 31; d < 384; d += 32) {
      float v = (d < 300) ? er[d] : (d < 350 ? mr[d - 300] : 0.f);
      x0b[(size_t)bt * 384 + d] = f2bf(v);
    }
  } else {
    int r = blk - 3456;           // 0..7, 20KB each -> 160KB (cbuf+flagsA+flagsB)
    float4* p = (float4*)zero_base + (size_t)r * 1280 + tid;
#pragma unroll
    for (int i = 0; i < 5; ++i) p[i * 256] = make_float4(0.f, 0.f, 0.f, 0.f);
  }
}

// ---- MFMA bf16 GEMM (fw+bw fused via z) -> xq[pos][2048][32] bf16 --------
__global__ __launch_bounds__(256) void gemm_xproj2(
    const unsigned short* __restrict__ A,     // [8192][Kpad] bf16
    const unsigned short* __restrict__ wxtF, const unsigned short* __restrict__ wxtB,
    const float* __restrict__ biasF, const float* __restrict__ biasB,
    unsigned short* __restrict__ xqF, unsigned short* __restrict__ xqB,
    int Kpad, int nkb)
{
  __shared__ unsigned short ws_s[128 * 64];
  __shared__ unsigned short xs_s[32 * 64];
  __shared__ float bias_s[128];
  int z = blockIdx.z;
  const unsigned short* wxt = z ? wxtB : wxtF;
  const float* bias = z ? biasB : biasF;
  unsigned short* xq = z ? xqB : xqF;
  int tid = threadIdx.x;
  int lane = tid & 63;
  int w = tid >> 6;
  int pos = blockIdx.x;
  int n0 = blockIdx.y * 128;
  if (tid < 128) bias_s[tid] = bias[n0 + tid];

  float4v acc[2][2];
#pragma unroll
  for (int i = 0; i < 2; ++i)
#pragma unroll
    for (int j = 0; j < 2; ++j) acc[i][j] = (float4v)0.f;

  int brow = tid >> 3;
  int seg = tid & 7;
  for (int kb = 0; kb < nkb; ++kb) {
    int k0 = kb * 64;
    __syncthreads();
    {
      const unsigned short* src = A + (size_t)(brow * 256 + pos) * Kpad + k0 + seg * 8;
      uint4 v = *(const uint4*)src;
      int o = (brow * 128 + seg * 16) ^ ((brow & 7) << 4);
      *(uint4*)((char*)xs_s + o) = v;
    }
#pragma unroll
    for (int i = 0; i < 4; ++i) {
      int n = i * 32 + brow;
      const unsigned short* src = wxt + (size_t)(n0 + n) * Kpad + k0 + seg * 8;
      uint4 v = *(const uint4*)src;
      int o = (n * 128 + seg * 16) ^ ((n & 7) << 4);
      *(uint4*)((char*)ws_s + o) = v;
    }
    __syncthreads();
#pragma unroll
    for (int kin = 0; kin < 64; kin += 32) {
      int kl = kin + ((lane >> 4) << 3);
      short8v afrag[2], bfrag[2];
#pragma unroll
      for (int nt = 0; nt < 2; ++nt) {
        int nl = w * 32 + nt * 16 + (lane & 15);
        int o = (nl * 128 + kl * 2) ^ ((nl & 7) << 4);
        afrag[nt] = *(const short8v*)((const char*)ws_s + o);
      }
#pragma unroll
      for (int bt = 0; bt < 2; ++bt) {
        int bl = bt * 16 + (lane & 15);
        int o = (bl * 128 + kl * 2) ^ ((bl & 7) << 4);
        bfrag[bt] = *(const short8v*)((const char*)xs_s + o);
      }
#pragma unroll
      for (int nt = 0; nt < 2; ++nt)
#pragma unroll
        for (int bt = 0; bt < 2; ++bt)
          acc[nt][bt] = __builtin_amdgcn_mfma_f32_16x16x32_bf16(
              afrag[nt], bfrag[bt], acc[nt][bt], 0, 0, 0);
    }
  }
  unsigned short* outp = xq + (size_t)pos * 65536;
#pragma unroll
  for (int nt = 0; nt < 2; ++nt) {
#pragma unroll
    for (int bt = 0; bt < 2; ++bt) {
#pragma unroll
      for (int reg = 0; reg < 4; ++reg) {
        int nl = w * 32 + nt * 16 + ((lane >> 4) << 2) + reg;
        int b = bt * 16 + (lane & 15);
        float v = acc[nt][bt][reg] + bias_s[nl];
        outp[(size_t)(n0 + nl) * 32 + b] = f2bf(v);
      }
    }
  }
}

// ================= MFMA bidirectional LSTM recurrence ==========
// R9 protocol (proven best) + A-fragments (step-invariant recurrent weights)
// hoisted into registers: Wl LDS region deleted, 16 ds_read_b128/step off the
// MFMA critical path. LDS now static 38KB.
__global__ __launch_bounds__(256) void lstm_mfma(
    const unsigned short* __restrict__ xq_fw, const unsigned short* __restrict__ xq_bw,
    const unsigned short* __restrict__ whT_fw, const unsigned short* __restrict__ whT_bw,
    const int* __restrict__ length,
    unsigned short* __restrict__ out,   // (B,T,1024) bf16
    unsigned short* __restrict__ hT,    // [dir][2][32][512] bf16
    float* __restrict__ cbuf,           // [dir][512][32] f32, fallback only
    int* __restrict__ flags,            // [dir][64][32] (layer-private area)
    int t0, int t1)
{
  __shared__ char hsmem[32768];              // [32 b][512 k] bf16, swz ^((b&7)<<4)
  __shared__ float zs[1024];                 // [32][32] f32
  __shared__ unsigned short hb_st[256];      // [32][8]
  __shared__ unsigned short ob_st[256];      // [32][8]
  int tid = threadIdx.x;
  int wg = blockIdx.x;
  int dir = wg >> 6;
  int widx = wg & 63;
  int u0 = widx << 3;
  const unsigned short* xq = dir ? xq_bw : xq_fw;
  const unsigned short* whT = dir ? whT_bw : whT_fw;
  unsigned short* hbase = hT + (size_t)dir * 32768;
  int* dirflags = flags + dir * 2048;
  int* myflag = dirflags + widx * 32;

  // wave/frag constants
  int lane = tid & 63;
  int w = tid >> 6;
  int wr = w >> 1, wc = w & 1;
  int arow = wr * 16 + (lane & 15);   // 0..31: gate-col row c=q*8+d of W slice
  int bcol = wc * 16 + (lane & 15);   // batch
  int chunk16 = (lane >> 4) << 4;     // k byte sub-offset
  int koff = (lane >> 4) << 3;        // k element sub-offset
  int bsw = (bcol & 7) << 4;
  // finalize constants
  int fu = tid >> 5;
  int fb = tid & 31;
  int ug = u0 + fu;
  int L = length[fb];
  float creg = 0.f;

  // ---- A-fragments: step-invariant, preload ONCE into registers ----
  short8v afrag[16];
  {
    int q = arow >> 3, dd = arow & 7;
    const unsigned short* arp = whT + (size_t)(q * 512 + u0 + dd) * 512;
#pragma unroll
    for (int ks = 0; ks < 16; ++ks)
      afrag[ks] = *(const short8v*)(arp + ks * 32 + koff);
  }

  // xv preload for t0
  const unsigned short* xbase = xq + (size_t)ug * 32 + fb;
  float xv0, xv1, xv2, xv3;
  {
    int sl0 = dir ? (TT - 1 - t0) : t0;
    const unsigned short* xr = xbase + (size_t)sl0 * 65536;
    xv0 = bf2f(xr[0]);
    xv1 = bf2f(xr[16384]);
    xv2 = bf2f(xr[32768]);
    xv3 = bf2f(xr[49152]);
  }

  for (int t = t0; t < t1; ++t) {
    int sl = dir ? (TT - 1 - t) : t;
    const unsigned short* hTr_g = hbase + (size_t)(t & 1) * 16384;
    unsigned short* hTw_g = hbase + (size_t)((t & 1) ^ 1) * 16384;

    // ---- h stage: t==0 -> zeros; else coherent 8x16B -> swizzled LDS ----
    {
      int row = tid >> 3;
      int ob = row * 1024 + (tid & 7) * 16;
      int sw = (row & 7) << 4;
      if (t == 0) {
        uint4v zv = (uint4v)0u;
#pragma unroll
        for (int i = 0; i < 8; ++i)
          *(uint4v*)(hsmem + ((ob + i * 128) ^ sw)) = zv;
      } else {
        const unsigned short* src = hTr_g + row * 512 + (tid & 7) * 8;
        uint4v r0, r1, r2, r3, r4, r5, r6, r7;
        ldg4u_cohere_issue(r0, src + 0 * 64);
        ldg4u_cohere_issue(r1, src + 1 * 64);
        ldg4u_cohere_issue(r2, src + 2 * 64);
        ldg4u_cohere_issue(r3, src + 3 * 64);
        ldg4u_cohere_issue(r4, src + 4 * 64);
        ldg4u_cohere_issue(r5, src + 5 * 64);
        ldg4u_cohere_issue(r6, src + 6 * 64);
        ldg4u_cohere_issue(r7, src + 7 * 64);
        wait_vm0();
        *(uint4v*)(hsmem + ((ob + 0 * 128) ^ sw)) = r0;
        *(uint4v*)(hsmem + ((ob + 1 * 128) ^ sw)) = r1;
        *(uint4v*)(hsmem + ((ob + 2 * 128) ^ sw)) = r2;
        *(uint4v*)(hsmem + ((ob + 3 * 128) ^ sw)) = r3;
        *(uint4v*)(hsmem + ((ob + 4 * 128) ^ sw)) = r4;
        *(uint4v*)(hsmem + ((ob + 5 * 128) ^ sw)) = r5;
        *(uint4v*)(hsmem + ((ob + 6 * 128) ^ sw)) = r6;
        *(uint4v*)(hsmem + ((ob + 7 * 128) ^ sw)) = r7;
      }
    }
    __syncthreads();

    // ---- MFMA: z[32 gate-cols][32 b] = W(32x512, regs) @ hs(512x32, LDS) --
    float4v acc = (float4v)0.f;
#pragma unroll
    for (int ks = 0; ks < 16; ++ks) {
      int kb = ks * 64 + chunk16;
      short8v bf = *(const short8v*)(hsmem + (size_t)bcol * 1024 + (kb ^ bsw));
      acc = __builtin_amdgcn_mfma_f32_16x16x32_bf16(afrag[ks], bf, acc, 0, 0, 0);
    }
#pragma unroll
    for (int r = 0; r < 4; ++r) {
      int row = wr * 16 + ((lane >> 4) << 2) + r;
      zs[row * 32 + bcol] = acc[r];
    }
    __syncthreads();

    // ---- finalize: all 256 threads, one (unit,batch) each ----
    {
      bool active = sl < L;
      float z0 = zs[(0 * 8 + fu) * 32 + fb] + xv0;
      float z1 = zs[(1 * 8 + fu) * 32 + fb] + xv1;
      float z2 = zs[(2 * 8 + fu) * 32 + fb] + xv2;
      float z3 = zs[(3 * 8 + fu) * 32 + fb] + xv3;
      int ho = fb * 1024 + ((ug * 2) ^ ((fb & 7) << 4));
      float h_old = bf2f(*(const unsigned short*)(hsmem + ho));
      float c_old = cbuf ? ((t > 0) ? cbuf[dir * 16384 + ug * 32 + fb] : 0.f) : creg;
      float si = fsig(z0);
      float sj = ftanh(z1);
      float sf = fsig(z2 + 1.f);
      float so = fsig(z3);
      float cn = sf * c_old + si * sj;
      float hn = so * ftanh(cn);
      if (active) {
        if (cbuf) cbuf[dir * 16384 + ug * 32 + fb] = cn; else creg = cn;
      }
      hb_st[fb * 8 + fu] = f2bf(active ? hn : h_old);
      ob_st[fb * 8 + fu] = f2bf(active ? hn : 0.f);
    }
    __syncthreads();

    if (tid < 32) {
      // wave 0 (lanes 0-31): coherent h broadcast store only
      uint4v hv = *(const uint4v*)(hb_st + tid * 8);
      asm volatile("global_store_dwordx4 %0, %1, off sc0 sc1"
                   :: "v"(hTw_g + tid * 512 + u0), "v"(hv) : "memory");
    } else if (tid >= 64 && tid < 96) {
      // wave 1: plain out store — never drained (stream order covers it)
      int b = tid - 64;
      uint4v ov = *(const uint4v*)(ob_st + b * 8);
      *(uint4v*)(out + (size_t)(b * TT + sl) * 1024 + dir * 512 + u0) = ov;
    }

    // prefetch next step's xv (plain loads; hidden under barrier poll)
    float nxv0 = 0.f, nxv1 = 0.f, nxv2 = 0.f, nxv3 = 0.f;
    if (t + 1 < t1) {
      int sl2 = dir ? (TT - 2 - t) : (t + 1);
      const unsigned short* xr = xbase + (size_t)sl2 * 65536;
      nxv0 = bf2f(xr[0]);
      nxv1 = bf2f(xr[16384]);
      nxv2 = bf2f(xr[32768]);
      nxv3 = bf2f(xr[49152]);
    }

    if (t1 - t0 > 1) {
      if (tid < 64) {               // wave 0 only: drain h-stores + post + poll
        wait_vm0();
        if (tid == 0) {
          __hip_atomic_store(myflag, t + 1, __ATOMIC_RELAXED,
                             __HIP_MEMORY_SCOPE_AGENT);
        }
        int* f = dirflags + tid * 32;
        while (__hip_atomic_load(f, __ATOMIC_RELAXED,
                                 __HIP_MEMORY_SCOPE_AGENT) < t + 1) {
          __builtin_amdgcn_s_sleep(1);
        }
      }
      __syncthreads();
    }
    xv0 = nxv0; xv1 = nxv1; xv2 = nxv2; xv3 = nxv3;
  }
}

// ---------------- CRF + pooling + final softmax ----------------
__global__ __launch_bounds__(256) void crf_final(
    const unsigned short* __restrict__ out1,   // (B,T,1024) bf16
    const float* __restrict__ crf_w, const float* __restrict__ crf_b,
    const float* __restrict__ trans,
    const int* __restrict__ length,
    const float* __restrict__ lw, const float* __restrict__ lb,
    float* __restrict__ dout)
{
  __shared__ float e[TT][2];
  __shared__ float pw[TT];
  __shared__ float sv[1024];
  __shared__ float red[256];
  int b = blockIdx.x, tid = threadIdx.x;
  int lane = tid & 63, w = tid >> 6;
  const unsigned short* ob = out1 + (size_t)b * TT * 1024;
  for (int t = w; t < TT; t += 4) {
    float a0 = 0.f, a1 = 0.f;
    for (int i = 0; i < 16; ++i) {
      int d = lane + i * 64;
      float v = bf2f(ob[(size_t)t * 1024 + d]);
      a0 += v * crf_w[d * 2];
      a1 += v * crf_w[d * 2 + 1];
    }
    for (int off = 32; off; off >>= 1) {
      a0 += __shfl_down(a0, off);
      a1 += __shfl_down(a1, off);
    }
    if (lane == 0) { e[t][0] = a0 + crf_b[0]; e[t][1] = a1 + crf_b[1]; }
  }
  __syncthreads();
  if (tid == 0) {
    int L = length[b];
    float t00 = trans[0], t01 = trans[1], t10 = trans[2], t11 = trans[3];
    float a0 = e[0][0], a1 = e[0][1];
    {
      float m = fmaxf(a0, a1);
      float e0 = __expf(a0 - m), e1 = __expf(a1 - m);
      pw[0] = (L > 0) ? (e1 / (e0 + e1)) : 0.f;
    }
    for (int t = 1; t < TT; ++t) {
      if (t < L) {
        float x0 = a0 + t00, y0 = a1 + t10;
        float m0 = fmaxf(x0, y0);
        float n0 = m0 + __logf(__expf(x0 - m0) + __expf(y0 - m0)) + e[t][0];
        float x1 = a0 + t01, y1 = a1 + t11;
        float m1 = fmaxf(x1, y1);
        float n1 = m1 + __logf(__expf(x1 - m1) + __expf(y1 - m1)) + e[t][1];
        a0 = n0; a1 = n1;
        float m = fmaxf(a0, a1);
        float e0 = __expf(a0 - m), e1 = __expf(a1 - m);
        pw[t] = e1 / (e0 + e1);
      } else {
        pw[t] = 0.f;
      }
    }
  }
  __syncthreads();
  for (int i = 0; i < 4; ++i) {
    int d = tid + i * 256;
    float s = 0.f;
    for (int t = 0; t < TT; ++t) s += pw[t] * bf2f(ob[(size_t)t * 1024 + d]);
    sv[d] = s;
  }
  __syncthreads();
  float v[3];
  for (int c = 0; c < 3; ++c) {
    float s = 0.f;
    for (int i = 0; i < 4; ++i) {
      int d = tid + i * 256;
      s += sv[d] * lw[d * 3 + c];
    }
    red[tid] = s;
    __syncthreads();
    for (int off = 128; off; off >>= 1) {
      if (tid < off) red[tid] += red[tid + off];
      __syncthreads();
    }
    if (tid == 0) v[c] = red[0] + lb[c];
    __syncthreads();
  }
  if (tid == 0) {
    float m = fmaxf(v[0], fmaxf(v[1], v[2]));
    float e0 = __expf(v[0] - m), e1 = __expf(v[1] - m), e2 = __expf(v[2] - m);
    float s = e0 + e1 + e2;
    dout[b * 3 + 0] = e0 / s;
    dout[b * 3 + 1] = e1 / s;
    dout[b * 3 + 2] = e2 / s;
  }
}

static void run_layer(const unsigned short* xq_fw, const unsigned short* xq_bw,
                      const unsigned short* whT_fw, const unsigned short* whT_bw,
                      const int* len, unsigned short* out, unsigned short* hT,
                      float* cbuf_, int* flags, hipStream_t stream) {
  const unsigned short* a0 = xq_fw; const unsigned short* a1 = xq_bw;
  const unsigned short* a2 = whT_fw; const unsigned short* a3 = whT_bw;
  const int* a4 = len; unsigned short* a5 = out; unsigned short* a6 = hT;
  float* a7 = nullptr; int* a8 = flags; int a9 = 0, a10 = TT;
  void* args[11] = { &a0, &a1, &a2, &a3, &a4, &a5, &a6, &a7, &a8, &a9, &a10 };
  hipError_t err = hipLaunchCooperativeKernel(
      reinterpret_cast<const void*>(lstm_mfma), dim3(128), dim3(256),
      args, 0, stream);
  if (err != hipSuccess) {
    for (int t = 0; t < TT; ++t) {
      lstm_mfma<<<128, 256, 0, stream>>>(
          xq_fw, xq_bw, whT_fw, whT_bw, len, out, hT, cbuf_, flags, t, t + 1);
    }
  }
}

extern "C" void kernel_launch(void* const* d_in, const int* in_sizes, int n_in,
                              void* d_out, int out_size, void* d_ws, size_t ws_size,
                              hipStream_t stream) {
  (void)in_sizes; (void)n_in; (void)out_size; (void)ws_size;
  const int* ids    = (const int*)d_in[0];
  const int* msk    = (const int*)d_in[1];
  const int* len    = (const int*)d_in[2];
  const float* emb  = (const float*)d_in[3];
  const float* memb = (const float*)d_in[4];
  const float* trans= (const float*)d_in[5];
  const float* w_fw0= (const float*)d_in[6];
  const float* b_fw0= (const float*)d_in[7];
  const float* w_bw0= (const float*)d_in[8];
  const float* b_bw0= (const float*)d_in[9];
  const float* w_fw1= (const float*)d_in[10];
  const float* b_fw1= (const float*)d_in[11];
  const float* w_bw1= (const float*)d_in[12];
  const float* b_bw1= (const float*)d_in[13];
  const float* crf_w= (const float*)d_in[14];
  const float* crf_b= (const float*)d_in[15];
  const float* lw   = (const float*)d_in[16];
  const float* lb   = (const float*)d_in[17];
  float* outp = (float*)d_out;

  float* ws = (float*)d_ws;
  unsigned short* x0b   = (unsigned short*)(ws);
  unsigned short* wxt0f = (unsigned short*)(ws + 1572864);
  unsigned short* wxt0b = (unsigned short*)(ws + 1966080);
  unsigned short* wxt1f = (unsigned short*)(ws + 2359296);
  unsigned short* wxt1b = (unsigned short*)(ws + 3407872);
  unsigned short* whT0f = (unsigned short*)(ws + 4456448);
  unsigned short* whT0b = (unsigned short*)(ws + 4980736);
  unsigned short* whT1f = (unsigned short*)(ws + 5505024);
  unsigned short* whT1b = (unsigned short*)(ws + 6029312);
  unsigned short* xqf   = (unsigned short*)(ws + 6553600);
  unsigned short* xqb   = (unsigned short*)(ws + 14942208);
  unsigned short* out0b = (unsigned short*)(ws + 23330816);
  unsigned short* out1b = (unsigned short*)(ws + 27525120);
  unsigned short* hT    = (unsigned short*)(ws + 31719424);
  float* cbuf_ = ws + 31752192;                 // 32768 f (128KB)
  int*   flagsA = (int*)(ws + 31784960);        // 4096 ints (16KB)
  int*   flagsB = (int*)(ws + 31789056);        // 4096 ints (16KB)

  // one launch: 8 weight transposes + embedding + zero cbuf/flagsA/flagsB
  prep_all<<<3464, 256, 0, stream>>>(
      w_fw0, w_bw0, w_fw1, w_bw1,
      wxt0f, wxt0b, wxt1f, wxt1b,
      whT0f, whT0b, whT1f, whT1b,
      ids, msk, emb, memb, x0b, cbuf_);

  gemm_xproj2<<<dim3(256, 16, 2), 256, 0, stream>>>(
      x0b, wxt0f, wxt0b, b_fw0, b_bw0, xqf, xqb, 384, 6);

  run_layer(xqf, xqb, whT0f, whT0b, len, out0b, hT, cbuf_, flagsA, stream);

  gemm_xproj2<<<dim3(256, 16, 2), 256, 0, stream>>>(
      out0b, wxt1f, wxt1b, b_fw1, b_bw1, xqf, xqb, 1024, 16);

  run_layer(xqf, xqb, whT1f, whT1b, len, out1b, hT, cbuf_, flagsB, stream);

  crf_final<<<32, 256, 0, stream>>>(out1b, crf_w, crf_b, trans, len, lw, lb, outp);
}